// Round 8
// baseline (2960.387 us; speedup 1.0000x reference)
//
#include <hip/hip_runtime.h>

#define B_   8
#define N_   8192
#define CIN  64
#define COUT 128
#define M_   2048
#define K_   16

// ---------------------------------------------------------------------------
// 1) Pointwise MLP: h = relu( (x @ W^T - mean) * rsqrt(var+eps) * gamma + beta )
// ---------------------------------------------------------------------------
__global__ __launch_bounds__(256) void mlp_kernel(
    const float* __restrict__ x, const float* __restrict__ W,
    const float* __restrict__ gamma, const float* __restrict__ beta,
    const float* __restrict__ rmean, const float* __restrict__ rvar,
    float* __restrict__ h) {
  int tid = blockIdx.x * 256 + threadIdx.x;      // [0, B*N*COUT)
  int o   = tid & (COUT - 1);
  int row = tid >> 7;                            // b*N + n
  const float4* xr = (const float4*)(x + (size_t)row * CIN);
  const float4* wr = (const float4*)(W + (size_t)o * CIN);
  float acc = 0.f;
#pragma unroll
  for (int c = 0; c < CIN / 4; c++) {
    float4 a = xr[c], w = wr[c];
    acc += a.x * w.x + a.y * w.y + a.z * w.z + a.w * w.w;
  }
  float v = (acc - rmean[o]) * rsqrtf(rvar[o] + 1e-5f) * gamma[o] + beta[o];
  h[tid] = fmaxf(v, 0.f);
}

// ---------------------------------------------------------------------------
// 2) FPS — numerics identical to R5-R7 passing chain (f32 strict numpy order
//    ((dx^2+dy^2)+dz^2) no-FMA, fminf, (max d, min n) argmax tie-break).
//    Latency restructure:
//    * key = [it:11 | f32bits(bd):32 | (N-1-n):13] — iteration tag makes keys
//      from iter it+1 beat any stale iter-it value => atomicMax needs NO
//      reset. Parity slots wslot[it&1]: reads of iter it are separated from
//      iter it+2 writes by barrier(it+1) => race-free, ONE barrier/iter.
//    * per-wave u64 butterfly -> 8 atomicMax (LDS, same addr) -> all threads
//      read ONE b64 slot.
//    * coords as float4 in LDS: winner fetch = 1 ds_read_b128.
// ---------------------------------------------------------------------------
#define FTH 512
#define FPT 16   // points per thread = N_/FTH

__global__ __launch_bounds__(512) void fps_kernel(
    const float* __restrict__ p, float* __restrict__ p_out) {
#pragma clang fp contract(off)
  __shared__ float4 pc4[N_];                    // 128 KB
  __shared__ unsigned long long wslot[2];
  __shared__ int idxHist[M_];                   // 8 KB

  const int b   = blockIdx.x;
  const int tid = threadIdx.x;
  const int ln  = tid & 63;

  // stage p[b] into LDS as float4 (one-time)
  const float* pb = p + (size_t)b * N_ * 3;
  for (int n = tid; n < N_; n += FTH)
    pc4[n] = make_float4(pb[3 * n + 0], pb[3 * n + 1], pb[3 * n + 2], 0.f);
  if (tid == 0) { idxHist[0] = 0; wslot[0] = 0ull; wslot[1] = 0ull; }
  __syncthreads();

  // current center (sample 0 = point 0)
  float4 c0 = pc4[0];
  float cx = c0.x, cy = c0.y, cz = c0.z;

  // my 16 points -> registers (n = tid + k*512)
  float X[FPT], Y[FPT], Z[FPT], D[FPT];
#pragma unroll
  for (int k = 0; k < FPT; k++) {
    float4 v = pc4[tid + k * FTH];
    X[k] = v.x; Y[k] = v.y; Z[k] = v.z;
    D[k] = __builtin_inff();
  }

  for (int it = 1; it < M_; ++it) {
    float bd = -1.0f; int bk = 0;
#pragma unroll
    for (int k = 0; k < FPT; k++) {
      float dx = X[k] - cx, dy = Y[k] - cy, dz = Z[k] - cz;
      float d  = (dx * dx + dy * dy) + dz * dz; // numpy sum order, no fma
      float dm = fminf(D[k], d);
      D[k] = dm;
      if (dm > bd) { bd = dm; bk = k; }         // strict > keeps min k (min n)
    }
    const int n = tid + (bk << 9);              // bk*512
    unsigned long long key =
        ((unsigned long long)it << 45) |
        ((unsigned long long)__float_as_uint(bd) << 13) |
        (unsigned)(N_ - 1 - n);                 // max key => max d, min n
#pragma unroll
    for (int off = 32; off >= 1; off >>= 1) {
      unsigned long long o = __shfl_xor(key, off);
      key = key > o ? key : o;
    }
    if (ln == 0) atomicMax(&wslot[it & 1], key);
    __syncthreads();                            // the ONLY barrier per iter
    const unsigned long long m = wslot[it & 1];
    const int nw = N_ - 1 - (int)(unsigned)(m & 0x1FFFu);
    float4 cc = pc4[nw];                        // 1 broadcast b128
    cx = cc.x; cy = cc.y; cz = cc.z;
    if (tid == 0) idxHist[it] = nw;
  }
  __syncthreads();

  // write p_out once at the end
  float* po = p_out + (size_t)b * M_ * 3;
  for (int mi = tid; mi < M_; mi += FTH) {
    float4 v = pc4[idxHist[mi]];
    po[mi * 3 + 0] = v.x;
    po[mi * 3 + 1] = v.y;
    po[mi * 3 + 2] = v.z;
  }
}

// ---------------------------------------------------------------------------
// 3) KNN — d2 bits & selection semantics identical to R5-R7 (f32 expansion
//    form, sq/sn no-FMA sums, BLAS k-ascending FMA-chain dot; global
//    (d2,index)-lexicographic top-16 == top_k set + tie-break).
//    Latency restructure (2 barriers per block total):
//    * wave w owns quarter [w*2048,(w+1)*2048), 32 pts/lane in registers.
//    * 16 WAVE-LOCAL extraction rounds (butterfly only, NO block barriers;
//      overlaps freely across resident blocks): per-lane top-3 cache,
//      pop-on-win, register rescan w/ mask when cache empties (<=16 pops).
//    * per-wave sorted top-16 -> LDS (64 keys) -> barrier -> ALL waves
//      redundantly bitonic-sort 64 keys (21 shfl stages) -> lanes 0..15 =
//      exact global top-16 (unique n => no equal keys => exact).
//    * fused gather/max-pool: wave w takes sorted ranks 4w..4w+3.
// ---------------------------------------------------------------------------
#define UMAXK 0xFFFFFFFFFFFFFFFFull

__global__ __launch_bounds__(256) void knn_kernel(
    const float* __restrict__ p, const float* __restrict__ p_out,
    const float* __restrict__ h, float* __restrict__ y) {
#pragma clang fp contract(off)
  __shared__ unsigned long long allk[64];
  __shared__ float2 pmax[4][64];

  const int q    = blockIdx.x;                  // b*M + m
  const int b    = q >> 11;                     // M_ = 2048
  const int t    = threadIdx.x;
  const int w    = t >> 6;
  const int lane = t & 63;

  const float qx = p_out[q * 3 + 0];
  const float qy = p_out[q * 3 + 1];
  const float qz = p_out[q * 3 + 2];
  const float sq = (qx * qx + qy * qy) + qz * qz;   // numpy sum, no fma

  const float* pb = p + (size_t)b * N_ * 3;
  const int base = (w << 11) + lane;            // wave quarter + lane
  float dv[32];
  unsigned long long k1 = UMAXK, k2 = UMAXK, k3 = UMAXK;
#pragma unroll
  for (int j = 0; j < 32; j++) {
    const int n = base + (j << 6);              // coalesced within wave
    float xx = pb[n * 3 + 0], yy = pb[n * 3 + 1], zz = pb[n * 3 + 2];
    float sn  = (xx * xx + yy * yy) + zz * zz;  // numpy sum, no fma
    float dot = __builtin_fmaf(qz, zz,
                __builtin_fmaf(qy, yy, qx * xx)); // BLAS fma chain, k asc
    float d2 = (sq + sn) - 2.0f * dot;
    dv[j] = d2;
    unsigned u = __float_as_uint(d2);
    u ^= (unsigned)((int)u >> 31) | 0x80000000u;  // monotone f32->u32
    unsigned long long key = ((unsigned long long)u << 32) | (unsigned)n;
    if (key < k1)      { k3 = k2; k2 = k1; k1 = key; }
    else if (key < k2) { k3 = k2; k2 = key; }
    else if (key < k3) { k3 = key; }
  }
  int count = 3;
  unsigned mask = 0;

  // 16 wave-local extraction rounds (no block barriers)
  unsigned long long mykey = UMAXK;             // lane r keeps round-r winner
  for (int k = 0; k < K_; k++) {
    unsigned long long key = (count > 0) ? k1 : UMAXK;
#pragma unroll
    for (int off = 32; off >= 1; off >>= 1) {
      unsigned long long o = __shfl_xor(key, off);
      key = key < o ? key : o;                  // unique n -> no ties
    }
    if (lane == k) mykey = key;
    const int nstar = (int)(unsigned)(key & 0xFFFFFFFFu);
    if (count > 0 && (int)(unsigned)(k1 & 0xFFFFFFFFu) == nstar) {
      mask |= 1u << ((nstar & 2047) >> 6);      // slot j of this lane
      k1 = k2; k2 = k3; k3 = UMAXK; count--;
      if (count == 0 && k < K_ - 1) {           // rare register rescan
        k1 = k2 = k3 = UMAXK;
#pragma unroll
        for (int j = 0; j < 32; j++) {
          if (!((mask >> j) & 1u)) {
            unsigned u = __float_as_uint(dv[j]);
            u ^= (unsigned)((int)u >> 31) | 0x80000000u;
            unsigned long long kk =
                ((unsigned long long)u << 32) | (unsigned)(base + (j << 6));
            if (kk < k1)      { k3 = k2; k2 = k1; k1 = kk; }
            else if (kk < k2) { k3 = k2; k2 = kk; }
            else if (kk < k3) { k3 = kk; }
          }
        }
        count = 3;
      }
    }
  }

  if (lane < K_) allk[(w << 4) + lane] = mykey;
  __syncthreads();                              // barrier 1

  // every wave redundantly sorts the 64 candidates (bitonic, ascending)
  unsigned long long key = allk[lane];
#pragma unroll
  for (int kk = 2; kk <= 64; kk <<= 1) {
#pragma unroll
    for (int jj = kk >> 1; jj > 0; jj >>= 1) {
      unsigned long long o = __shfl_xor(key, jj);
      bool keepMin = ((lane & kk) == 0) == ((lane & jj) == 0);
      unsigned long long mn = key < o ? key : o;
      unsigned long long mx = key < o ? o : key;
      key = keepMin ? mn : mx;
    }
  }
  // lanes 0..15 now hold the exact global top-16 (ascending d2, then n)

  // fused gather + max-pool: wave w covers sorted ranks 4w..4w+3
  const float* hb = h + (size_t)b * N_ * COUT;
  float2 acc = make_float2(-__builtin_inff(), -__builtin_inff());
#pragma unroll
  for (int i = 0; i < 4; i++) {
    int nn = (int)(unsigned)(__shfl(key, (w << 2) + i) & 0xFFFFFFFFu);
    float2 v = *(const float2*)(hb + (size_t)nn * COUT + lane * 2);
    acc.x = fmaxf(acc.x, v.x);
    acc.y = fmaxf(acc.y, v.y);
  }
  pmax[w][lane] = acc;
  __syncthreads();                              // barrier 2
  if (w == 0) {
    float2 a0 = pmax[0][lane], a1 = pmax[1][lane];
    float2 a2 = pmax[2][lane], a3 = pmax[3][lane];
    float2 r;
    r.x = fmaxf(fmaxf(a0.x, a1.x), fmaxf(a2.x, a3.x));
    r.y = fmaxf(fmaxf(a0.y, a1.y), fmaxf(a2.y, a3.y));
    *(float2*)(y + (size_t)q * COUT + lane * 2) = r;
  }
}

// ---------------------------------------------------------------------------
extern "C" void kernel_launch(void* const* d_in, const int* in_sizes, int n_in,
                              void* d_out, int out_size, void* d_ws, size_t ws_size,
                              hipStream_t stream) {
  const float* x     = (const float*)d_in[0];
  const float* p     = (const float*)d_in[1];
  const float* W     = (const float*)d_in[2];
  const float* gamma = (const float*)d_in[3];
  const float* beta  = (const float*)d_in[4];
  const float* rmean = (const float*)d_in[5];
  const float* rvar  = (const float*)d_in[6];

  float* y     = (float*)d_out;                       // (B, M, COUT)
  float* p_out = y + (size_t)B_ * M_ * COUT;          // (B, M, 3)
  float* h     = (float*)d_ws;                        // (B, N, COUT) scratch

  mlp_kernel<<<(B_ * N_ * COUT) / 256, 256, 0, stream>>>(
      x, W, gamma, beta, rmean, rvar, h);
  fps_kernel<<<B_, FTH, 0, stream>>>(p, p_out);
  knn_kernel<<<B_ * M_, 256, 0, stream>>>(p, p_out, h, y);
}

// Round 9
// 2555.719 us; speedup vs baseline: 1.1583x; 1.1583x over previous
//
#include <hip/hip_runtime.h>

#define B_   8
#define N_   8192
#define CIN  64
#define COUT 128
#define M_   2048
#define K_   16

// ---------------------------------------------------------------------------
// DPP wave-64 reduce helpers (VALU-only, no LDS latency).
// row_shr:1/2/4/8 accumulate within 16-lane rows; bcast15/bcast31 cross rows;
// lane 63 ends with the full reduction; v_readlane broadcasts it (SGPR).
// update_dpp(old=own, ...) keeps own value on masked/invalid lanes, which is
// the correct identity for both max and min.
// ---------------------------------------------------------------------------
template <int CTRL>
__device__ __forceinline__ unsigned long long dpp64(unsigned long long x) {
  int lo = (int)(unsigned)(x & 0xFFFFFFFFull);
  int hi = (int)(unsigned)(x >> 32);
  int dlo = __builtin_amdgcn_update_dpp(lo, lo, CTRL, 0xF, 0xF, false);
  int dhi = __builtin_amdgcn_update_dpp(hi, hi, CTRL, 0xF, 0xF, false);
  return ((unsigned long long)(unsigned)dhi << 32) | (unsigned)dlo;
}

__device__ __forceinline__ unsigned long long readlane63_u64(unsigned long long k) {
  unsigned lo = (unsigned)__builtin_amdgcn_readlane((int)(unsigned)(k & 0xFFFFFFFFull), 63);
  unsigned hi = (unsigned)__builtin_amdgcn_readlane((int)(unsigned)(k >> 32), 63);
  return ((unsigned long long)hi << 32) | lo;
}

__device__ __forceinline__ unsigned long long wave_max_u64(unsigned long long k) {
  unsigned long long t;
  t = dpp64<0x111>(k); k = t > k ? t : k;   // row_shr:1
  t = dpp64<0x112>(k); k = t > k ? t : k;   // row_shr:2
  t = dpp64<0x114>(k); k = t > k ? t : k;   // row_shr:4
  t = dpp64<0x118>(k); k = t > k ? t : k;   // row_shr:8
  t = dpp64<0x142>(k); k = t > k ? t : k;   // row_bcast:15
  t = dpp64<0x143>(k); k = t > k ? t : k;   // row_bcast:31
  return readlane63_u64(k);                 // uniform
}

__device__ __forceinline__ unsigned long long wave_min_u64(unsigned long long k) {
  unsigned long long t;
  t = dpp64<0x111>(k); k = t < k ? t : k;
  t = dpp64<0x112>(k); k = t < k ? t : k;
  t = dpp64<0x114>(k); k = t < k ? t : k;
  t = dpp64<0x118>(k); k = t < k ? t : k;
  t = dpp64<0x142>(k); k = t < k ? t : k;
  t = dpp64<0x143>(k); k = t < k ? t : k;
  return readlane63_u64(k);                 // uniform
}

// ---------------------------------------------------------------------------
// 1) Pointwise MLP: h = relu( (x @ W^T - mean) * rsqrt(var+eps) * gamma + beta )
// ---------------------------------------------------------------------------
__global__ __launch_bounds__(256) void mlp_kernel(
    const float* __restrict__ x, const float* __restrict__ W,
    const float* __restrict__ gamma, const float* __restrict__ beta,
    const float* __restrict__ rmean, const float* __restrict__ rvar,
    float* __restrict__ h) {
  int tid = blockIdx.x * 256 + threadIdx.x;      // [0, B*N*COUT)
  int o   = tid & (COUT - 1);
  int row = tid >> 7;                            // b*N + n
  const float4* xr = (const float4*)(x + (size_t)row * CIN);
  const float4* wr = (const float4*)(W + (size_t)o * CIN);
  float acc = 0.f;
#pragma unroll
  for (int c = 0; c < CIN / 4; c++) {
    float4 a = xr[c], w = wr[c];
    acc += a.x * w.x + a.y * w.y + a.z * w.z + a.w * w.w;
  }
  float v = (acc - rmean[o]) * rsqrtf(rvar[o] + 1e-5f) * gamma[o] + beta[o];
  h[tid] = fmaxf(v, 0.f);
}

// ---------------------------------------------------------------------------
// 2) FPS — numerics identical to R5-R8 passing chain (f32 strict numpy order
//    ((dx^2+dy^2)+dz^2) no-FMA, fminf, u64 (d<<32)|(N-1-n) => (max d, min n)).
//    Structure: R7's wred[2][8] one-barrier scheme (fastest so far), but the
//    wave butterfly (6 dependent LDS-permute stages ~750 cyc) is replaced by
//    the DPP reduce (~130 cyc, VALU-only). Decode reads wred as 4×b128.
// ---------------------------------------------------------------------------
#define FTH 512
#define FPT 16   // points per thread = N_/FTH

__global__ __launch_bounds__(512) void fps_kernel(
    const float* __restrict__ p, float* __restrict__ p_out) {
#pragma clang fp contract(off)
  __shared__ float4 pc4[N_];                            // 128 KB
  __shared__ __align__(16) unsigned long long wred[2][8];
  __shared__ int idxHist[M_];                           // 8 KB

  const int b   = blockIdx.x;
  const int tid = threadIdx.x;
  const int wv  = tid >> 6;
  const int ln  = tid & 63;

  // stage p[b] into LDS as float4 (one-time)
  const float* pb = p + (size_t)b * N_ * 3;
  for (int n = tid; n < N_; n += FTH)
    pc4[n] = make_float4(pb[3 * n + 0], pb[3 * n + 1], pb[3 * n + 2], 0.f);
  if (tid == 0) idxHist[0] = 0;
  __syncthreads();

  // current center (sample 0 = point 0)
  float4 c0 = pc4[0];
  float cx = c0.x, cy = c0.y, cz = c0.z;

  // my 16 points -> registers (n = tid + k*512)
  float X[FPT], Y[FPT], Z[FPT], D[FPT];
#pragma unroll
  for (int k = 0; k < FPT; k++) {
    float4 v = pc4[tid + k * FTH];
    X[k] = v.x; Y[k] = v.y; Z[k] = v.z;
    D[k] = __builtin_inff();
  }

  int buf = 0;
  for (int it = 1; it < M_; ++it) {
    float bd = -1.0f; int bk = 0;
#pragma unroll
    for (int k = 0; k < FPT; k++) {
      float dx = X[k] - cx, dy = Y[k] - cy, dz = Z[k] - cz;
      float d  = (dx * dx + dy * dy) + dz * dz; // numpy sum order, no fma
      float dm = fminf(D[k], d);
      D[k] = dm;
      if (dm > bd) { bd = dm; bk = k; }         // strict > keeps min k (min n)
    }
    const int n = tid + (bk << 9);              // bk*512
    unsigned long long key =
        ((unsigned long long)__float_as_uint(bd) << 32) |
        (unsigned)(N_ - 1 - n);                 // max key => max d, min n
    key = wave_max_u64(key);                    // DPP reduce (uniform result)
    if (ln == 0) wred[buf][wv] = key;
    __syncthreads();                            // the ONLY barrier per iter
    const ulonglong2* wp = (const ulonglong2*)(&wred[buf][0]);
    ulonglong2 w0 = wp[0], w1 = wp[1], w2 = wp[2], w3 = wp[3];
    unsigned long long m0 = w0.x > w0.y ? w0.x : w0.y;
    unsigned long long m1 = w1.x > w1.y ? w1.x : w1.y;
    unsigned long long m2 = w2.x > w2.y ? w2.x : w2.y;
    unsigned long long m3 = w3.x > w3.y ? w3.x : w3.y;
    m0 = m0 > m1 ? m0 : m1;
    m2 = m2 > m3 ? m2 : m3;
    m0 = m0 > m2 ? m0 : m2;
    const int nw = N_ - 1 - (int)(unsigned)(m0 & 0xFFFFFFFFu);
    float4 cc = pc4[nw];                        // 1 broadcast b128
    cx = cc.x; cy = cc.y; cz = cc.z;
    if (tid == 0) idxHist[it] = nw;
    buf ^= 1;
  }
  __syncthreads();

  // write p_out once at the end
  float* po = p_out + (size_t)b * M_ * 3;
  for (int mi = tid; mi < M_; mi += FTH) {
    float4 v = pc4[idxHist[mi]];
    po[mi * 3 + 0] = v.x;
    po[mi * 3 + 1] = v.y;
    po[mi * 3 + 2] = v.z;
  }
}

// ---------------------------------------------------------------------------
// 3) KNN — d2 bits & selection semantics identical to R5-R8 (f32 expansion
//    form, sq/sn no-FMA sums, BLAS k-ascending FMA-chain dot; global
//    (d2,index)-lexicographic top-16 == top_k set + tie-break).
//    * wave w owns quarter [w*2048,(w+1)*2048), 32 pts/lane in registers;
//      per-lane top-3 cache + pop-on-win + rare register rescan (as R8).
//    * 16 wave-local extraction rounds now use the DPP min-reduce
//      (~150 cyc VALU chain vs ~750 cyc LDS-permute butterfly).
//    * cross-wave merge: all-pairs RANK of the 64 candidates via broadcast
//      LDS reads (no dependent shuffle chains; exact for unique keys);
//      ranks 0..15 are the global top-16.
// ---------------------------------------------------------------------------
#define UMAXK 0xFFFFFFFFFFFFFFFFull

__global__ __launch_bounds__(256) void knn_kernel(
    const float* __restrict__ p, const float* __restrict__ p_out,
    const float* __restrict__ h, float* __restrict__ y) {
#pragma clang fp contract(off)
  __shared__ unsigned long long allk[64];
  __shared__ unsigned long long wsl[K_];
  __shared__ float2 pmax[4][64];

  const int q    = blockIdx.x;                  // b*M + m
  const int b    = q >> 11;                     // M_ = 2048
  const int t    = threadIdx.x;
  const int w    = t >> 6;
  const int lane = t & 63;

  const float qx = p_out[q * 3 + 0];
  const float qy = p_out[q * 3 + 1];
  const float qz = p_out[q * 3 + 2];
  const float sq = (qx * qx + qy * qy) + qz * qz;   // numpy sum, no fma

  const float* pb = p + (size_t)b * N_ * 3;
  const int base = (w << 11) + lane;            // wave quarter + lane
  float dv[32];
  unsigned long long k1 = UMAXK, k2 = UMAXK, k3 = UMAXK;
#pragma unroll
  for (int j = 0; j < 32; j++) {
    const int n = base + (j << 6);              // coalesced within wave
    float xx = pb[n * 3 + 0], yy = pb[n * 3 + 1], zz = pb[n * 3 + 2];
    float sn  = (xx * xx + yy * yy) + zz * zz;  // numpy sum, no fma
    float dot = __builtin_fmaf(qz, zz,
                __builtin_fmaf(qy, yy, qx * xx)); // BLAS fma chain, k asc
    float d2 = (sq + sn) - 2.0f * dot;
    dv[j] = d2;
    unsigned u = __float_as_uint(d2);
    u ^= (unsigned)((int)u >> 31) | 0x80000000u;  // monotone f32->u32
    unsigned long long key = ((unsigned long long)u << 32) | (unsigned)n;
    if (key < k1)      { k3 = k2; k2 = k1; k1 = key; }
    else if (key < k2) { k3 = k2; k2 = key; }
    else if (key < k3) { k3 = key; }
  }
  int count = 3;
  unsigned mask = 0;

  // 16 wave-local extraction rounds (DPP reduce; no block barriers)
  unsigned long long mykey = UMAXK;             // lane r keeps round-r winner
  for (int k = 0; k < K_; k++) {
    unsigned long long cnd = (count > 0) ? k1 : UMAXK;
    unsigned long long win = wave_min_u64(cnd); // uniform
    if (lane == k) mykey = win;
    const int nstar = (int)(unsigned)(win & 0xFFFFFFFFu);
    if (count > 0 && (int)(unsigned)(k1 & 0xFFFFFFFFu) == nstar) {
      mask |= 1u << ((nstar & 2047) >> 6);      // slot j of this lane
      k1 = k2; k2 = k3; k3 = UMAXK; count--;
      if (count == 0 && k < K_ - 1) {           // rare register rescan
        k1 = k2 = k3 = UMAXK;
#pragma unroll
        for (int j = 0; j < 32; j++) {
          if (!((mask >> j) & 1u)) {
            unsigned u = __float_as_uint(dv[j]);
            u ^= (unsigned)((int)u >> 31) | 0x80000000u;
            unsigned long long kk =
                ((unsigned long long)u << 32) | (unsigned)(base + (j << 6));
            if (kk < k1)      { k3 = k2; k2 = k1; k1 = kk; }
            else if (kk < k2) { k3 = k2; k2 = kk; }
            else if (kk < k3) { k3 = kk; }
          }
        }
        count = 3;
      }
    }
  }

  if (lane < K_) allk[(w << 4) + lane] = mykey;
  __syncthreads();

  // all-pairs rank merge of the 64 candidates (keys unique => exact)
  unsigned long long mine = allk[lane];
  int rank = 0;
#pragma unroll
  for (int j = 0; j < 64; j++) {
    unsigned long long kj = allk[j];            // broadcast read
    rank += (kj < mine) ? 1 : 0;
  }
  if (rank < K_) wsl[rank] = mine;              // global top-16 by rank
  __syncthreads();

  // fused gather + max-pool: wave w covers ranks 4w..4w+3
  const float* hb = h + (size_t)b * N_ * COUT;
  float2 acc = make_float2(-__builtin_inff(), -__builtin_inff());
#pragma unroll
  for (int i = 0; i < 4; i++) {
    unsigned long long kk = wsl[(w << 2) + i];  // broadcast read
    const int nn = (int)(unsigned)(kk & 0xFFFFFFFFu);
    float2 v = *(const float2*)(hb + (size_t)nn * COUT + lane * 2);
    acc.x = fmaxf(acc.x, v.x);
    acc.y = fmaxf(acc.y, v.y);
  }
  pmax[w][lane] = acc;
  __syncthreads();
  if (w == 0) {
    float2 a0 = pmax[0][lane], a1 = pmax[1][lane];
    float2 a2 = pmax[2][lane], a3 = pmax[3][lane];
    float2 r;
    r.x = fmaxf(fmaxf(a0.x, a1.x), fmaxf(a2.x, a3.x));
    r.y = fmaxf(fmaxf(a0.y, a1.y), fmaxf(a2.y, a3.y));
    *(float2*)(y + (size_t)q * COUT + lane * 2) = r;
  }
}

// ---------------------------------------------------------------------------
extern "C" void kernel_launch(void* const* d_in, const int* in_sizes, int n_in,
                              void* d_out, int out_size, void* d_ws, size_t ws_size,
                              hipStream_t stream) {
  const float* x     = (const float*)d_in[0];
  const float* p     = (const float*)d_in[1];
  const float* W     = (const float*)d_in[2];
  const float* gamma = (const float*)d_in[3];
  const float* beta  = (const float*)d_in[4];
  const float* rmean = (const float*)d_in[5];
  const float* rvar  = (const float*)d_in[6];

  float* y     = (float*)d_out;                       // (B, M, COUT)
  float* p_out = y + (size_t)B_ * M_ * COUT;          // (B, M, 3)
  float* h     = (float*)d_ws;                        // (B, N, COUT) scratch

  mlp_kernel<<<(B_ * N_ * COUT) / 256, 256, 0, stream>>>(
      x, W, gamma, beta, rmean, rvar, h);
  fps_kernel<<<B_, FTH, 0, stream>>>(p, p_out);
  knn_kernel<<<B_ * M_, 256, 0, stream>>>(p, p_out, h, y);
}

// Round 10
// 2537.841 us; speedup vs baseline: 1.1665x; 1.0070x over previous
//
#include <hip/hip_runtime.h>

#define B_   8
#define N_   8192
#define CIN  64
#define COUT 128
#define M_   2048
#define K_   16

// ---------------------------------------------------------------------------
// DPP wave-64 reduce helpers (VALU-only, no LDS latency).
// ---------------------------------------------------------------------------
template <int CTRL>
__device__ __forceinline__ unsigned long long dpp64(unsigned long long x) {
  int lo = (int)(unsigned)(x & 0xFFFFFFFFull);
  int hi = (int)(unsigned)(x >> 32);
  int dlo = __builtin_amdgcn_update_dpp(lo, lo, CTRL, 0xF, 0xF, false);
  int dhi = __builtin_amdgcn_update_dpp(hi, hi, CTRL, 0xF, 0xF, false);
  return ((unsigned long long)(unsigned)dhi << 32) | (unsigned)dlo;
}

__device__ __forceinline__ unsigned long long readlane63_u64(unsigned long long k) {
  unsigned lo = (unsigned)__builtin_amdgcn_readlane((int)(unsigned)(k & 0xFFFFFFFFull), 63);
  unsigned hi = (unsigned)__builtin_amdgcn_readlane((int)(unsigned)(k >> 32), 63);
  return ((unsigned long long)hi << 32) | lo;
}

__device__ __forceinline__ unsigned long long wave_max_u64(unsigned long long k) {
  unsigned long long t;
  t = dpp64<0x111>(k); k = t > k ? t : k;   // row_shr:1
  t = dpp64<0x112>(k); k = t > k ? t : k;   // row_shr:2
  t = dpp64<0x114>(k); k = t > k ? t : k;   // row_shr:4
  t = dpp64<0x118>(k); k = t > k ? t : k;   // row_shr:8
  t = dpp64<0x142>(k); k = t > k ? t : k;   // row_bcast:15
  t = dpp64<0x143>(k); k = t > k ? t : k;   // row_bcast:31
  return readlane63_u64(k);
}

__device__ __forceinline__ unsigned long long wave_min_u64(unsigned long long k) {
  unsigned long long t;
  t = dpp64<0x111>(k); k = t < k ? t : k;
  t = dpp64<0x112>(k); k = t < k ? t : k;
  t = dpp64<0x114>(k); k = t < k ? t : k;
  t = dpp64<0x118>(k); k = t < k ? t : k;
  t = dpp64<0x142>(k); k = t < k ? t : k;
  t = dpp64<0x143>(k); k = t < k ? t : k;
  return readlane63_u64(k);
}

// ---------------------------------------------------------------------------
// 1) Pointwise MLP (unchanged, verified)
// ---------------------------------------------------------------------------
__global__ __launch_bounds__(256) void mlp_kernel(
    const float* __restrict__ x, const float* __restrict__ W,
    const float* __restrict__ gamma, const float* __restrict__ beta,
    const float* __restrict__ rmean, const float* __restrict__ rvar,
    float* __restrict__ h) {
  int tid = blockIdx.x * 256 + threadIdx.x;      // [0, B*N*COUT)
  int o   = tid & (COUT - 1);
  int row = tid >> 7;                            // b*N + n
  const float4* xr = (const float4*)(x + (size_t)row * CIN);
  const float4* wr = (const float4*)(W + (size_t)o * CIN);
  float acc = 0.f;
#pragma unroll
  for (int c = 0; c < CIN / 4; c++) {
    float4 a = xr[c], w = wr[c];
    acc += a.x * w.x + a.y * w.y + a.z * w.z + a.w * w.w;
  }
  float v = (acc - rmean[o]) * rsqrtf(rvar[o] + 1e-5f) * gamma[o] + beta[o];
  h[tid] = fmaxf(v, 0.f);
}

// ---------------------------------------------------------------------------
// 2) FPS — VERBATIM from R9 (passing, 1973 us). Numerics: f32 strict numpy
//    order ((dx^2+dy^2)+dz^2) no-FMA, fminf, u64 (d<<32)|(N-1-n) argmax.
// ---------------------------------------------------------------------------
#define FTH 512
#define FPT 16   // points per thread = N_/FTH

__global__ __launch_bounds__(512) void fps_kernel(
    const float* __restrict__ p, float* __restrict__ p_out) {
#pragma clang fp contract(off)
  __shared__ float4 pc4[N_];                            // 128 KB
  __shared__ __align__(16) unsigned long long wred[2][8];
  __shared__ int idxHist[M_];                           // 8 KB

  const int b   = blockIdx.x;
  const int tid = threadIdx.x;
  const int wv  = tid >> 6;
  const int ln  = tid & 63;

  const float* pb = p + (size_t)b * N_ * 3;
  for (int n = tid; n < N_; n += FTH)
    pc4[n] = make_float4(pb[3 * n + 0], pb[3 * n + 1], pb[3 * n + 2], 0.f);
  if (tid == 0) idxHist[0] = 0;
  __syncthreads();

  float4 c0 = pc4[0];
  float cx = c0.x, cy = c0.y, cz = c0.z;

  float X[FPT], Y[FPT], Z[FPT], D[FPT];
#pragma unroll
  for (int k = 0; k < FPT; k++) {
    float4 v = pc4[tid + k * FTH];
    X[k] = v.x; Y[k] = v.y; Z[k] = v.z;
    D[k] = __builtin_inff();
  }

  int buf = 0;
  for (int it = 1; it < M_; ++it) {
    float bd = -1.0f; int bk = 0;
#pragma unroll
    for (int k = 0; k < FPT; k++) {
      float dx = X[k] - cx, dy = Y[k] - cy, dz = Z[k] - cz;
      float d  = (dx * dx + dy * dy) + dz * dz; // numpy sum order, no fma
      float dm = fminf(D[k], d);
      D[k] = dm;
      if (dm > bd) { bd = dm; bk = k; }         // strict > keeps min k (min n)
    }
    const int n = tid + (bk << 9);              // bk*512
    unsigned long long key =
        ((unsigned long long)__float_as_uint(bd) << 32) |
        (unsigned)(N_ - 1 - n);                 // max key => max d, min n
    key = wave_max_u64(key);                    // DPP reduce (uniform result)
    if (ln == 0) wred[buf][wv] = key;
    __syncthreads();                            // the ONLY barrier per iter
    const ulonglong2* wp = (const ulonglong2*)(&wred[buf][0]);
    ulonglong2 w0 = wp[0], w1 = wp[1], w2 = wp[2], w3 = wp[3];
    unsigned long long m0 = w0.x > w0.y ? w0.x : w0.y;
    unsigned long long m1 = w1.x > w1.y ? w1.x : w1.y;
    unsigned long long m2 = w2.x > w2.y ? w2.x : w2.y;
    unsigned long long m3 = w3.x > w3.y ? w3.x : w3.y;
    m0 = m0 > m1 ? m0 : m1;
    m2 = m2 > m3 ? m2 : m3;
    m0 = m0 > m2 ? m0 : m2;
    const int nw = N_ - 1 - (int)(unsigned)(m0 & 0xFFFFFFFFu);
    float4 cc = pc4[nw];                        // 1 broadcast b128
    cx = cc.x; cy = cc.y; cz = cc.z;
    if (tid == 0) idxHist[it] = nw;
    buf ^= 1;
  }
  __syncthreads();

  float* po = p_out + (size_t)b * M_ * 3;
  for (int mi = tid; mi < M_; mi += FTH) {
    float4 v = pc4[idxHist[mi]];
    po[mi * 3 + 0] = v.x;
    po[mi * 3 + 1] = v.y;
    po[mi * 3 + 2] = v.z;
  }
}

// ---------------------------------------------------------------------------
// 3) KNN — restructured: 16 queries per block (1 wave = 1 query), p[b]
//    staged ONCE per block in LDS as float4(x,y,z,sn). Kills the per-block
//    96-scalar-global-load latency wall (R7-R9's real knn cost).
//    d2 bits & selection semantics identical to R5-R9:
//      sq/sn = (a^2+b^2)+c^2 no-FMA; dot = fma(qz,zz,fma(qy,yy,qx*xx));
//      d2 = (sq+sn) - 2*dot; global (d2,n)-lexicographic top-16 via
//      u64 (mono32(d2)<<32|n) min extraction = top_k set + tie-break.
//    Per lane: 128 pts, sorted top-4 register cache (guarded bubble insert),
//    16 DPP-min rounds, pop-on-win, 128-bit mask + rare LDS rescan (exact).
// ---------------------------------------------------------------------------
#define UMAXK 0xFFFFFFFFFFFFFFFFull
#define QPB  16   // queries (waves) per block

__global__ __launch_bounds__(1024) void knn_kernel(
    const float* __restrict__ p, const float* __restrict__ p_out,
    const float* __restrict__ h, float* __restrict__ y) {
#pragma clang fp contract(off)
  __shared__ float4 pc4[N_];            // 128 KB: x,y,z,sn
  __shared__ int winLds[QPB][K_];

  const int t    = threadIdx.x;
  const int wv   = t >> 6;
  const int lane = t & 63;
  const int b    = blockIdx.x & 7;      // batch: keeps h[b] on one XCD (heur.)
  const int grp  = blockIdx.x >> 3;     // 0..127
  const int q    = b * M_ + grp * QPB + wv;

  // stage p[b] + sn into LDS (once per block)
  const float* pb = p + (size_t)b * N_ * 3;
  for (int n = t; n < N_; n += 1024) {
    float xx = pb[3 * n + 0], yy = pb[3 * n + 1], zz = pb[3 * n + 2];
    float sn = (xx * xx + yy * yy) + zz * zz;   // numpy sum, no fma
    pc4[n] = make_float4(xx, yy, zz, sn);
  }
  __syncthreads();

  const float qx = p_out[q * 3 + 0];
  const float qy = p_out[q * 3 + 1];
  const float qz = p_out[q * 3 + 2];
  const float sq = (qx * qx + qy * qy) + qz * qz;   // numpy sum, no fma

  // scan 128 pts/lane from LDS; sorted top-4 cache c0<=c1<=c2<=c3
  unsigned long long c0 = UMAXK, c1 = UMAXK, c2 = UMAXK, c3 = UMAXK;
#pragma unroll 4
  for (int j = 0; j < 128; j++) {
    const int n = lane + (j << 6);
    float4 v = pc4[n];
    float dot = __builtin_fmaf(qz, v.z,
                __builtin_fmaf(qy, v.y, qx * v.x)); // BLAS fma chain, k asc
    float d2 = (sq + v.w) - 2.0f * dot;
    unsigned u = __float_as_uint(d2);
    u ^= (unsigned)((int)u >> 31) | 0x80000000u;    // monotone f32->u32
    unsigned long long key = ((unsigned long long)u << 32) | (unsigned)n;
    if (key < c3) {
      unsigned long long x = key, mn;
      mn = x < c0 ? x : c0; x = x < c0 ? c0 : x; c0 = mn;
      mn = x < c1 ? x : c1; x = x < c1 ? c1 : x; c1 = mn;
      mn = x < c2 ? x : c2; x = x < c2 ? c2 : x; c2 = mn;
      c3 = x < c3 ? x : c3;
    }
  }

  int count = 4;
  unsigned long long em0 = 0ull, em1 = 0ull;    // extraction mask (128 bits)
  unsigned long long mykey = UMAXK;             // lane r keeps round-r winner

  for (int k = 0; k < K_; k++) {
    unsigned long long cnd = (count > 0) ? c0 : UMAXK;
    unsigned long long win = wave_min_u64(cnd); // uniform; unique n => exact
    if (lane == k) mykey = win;
    const int nstar = (int)(unsigned)(win & 0xFFFFFFFFu);
    if ((nstar & 63) == lane) {                 // I own the winner (== my c0)
      const int j = nstar >> 6;
      if (j < 64) em0 |= 1ull << j; else em1 |= 1ull << (j - 64);
      c0 = c1; c1 = c2; c2 = c3; c3 = UMAXK; count--;
      if (count == 0 && k < K_ - 1) {           // rare exact rescan from LDS
        c0 = c1 = c2 = c3 = UMAXK;
        for (int j2 = 0; j2 < 128; j2++) {
          bool ex = (j2 < 64) ? ((em0 >> j2) & 1ull) : ((em1 >> (j2 - 64)) & 1ull);
          if (!ex) {
            const int n2 = lane + (j2 << 6);
            float4 v = pc4[n2];
            float dot = __builtin_fmaf(qz, v.z,
                        __builtin_fmaf(qy, v.y, qx * v.x));
            float d2 = (sq + v.w) - 2.0f * dot;
            unsigned u = __float_as_uint(d2);
            u ^= (unsigned)((int)u >> 31) | 0x80000000u;
            unsigned long long kk = ((unsigned long long)u << 32) | (unsigned)n2;
            if (kk < c3) {
              unsigned long long x = kk, mn;
              mn = x < c0 ? x : c0; x = x < c0 ? c0 : x; c0 = mn;
              mn = x < c1 ? x : c1; x = x < c1 ? c1 : x; c1 = mn;
              mn = x < c2 ? x : c2; x = x < c2 ? c2 : x; c2 = mn;
              c3 = x < c3 ? x : c3;
            }
          }
        }
        count = 4;
      }
    }
  }

  if (lane < K_) winLds[wv][lane] = (int)(unsigned)(mykey & 0xFFFFFFFFu);
  __syncthreads();

  // fused gather + max-pool: this wave's query, 16 rows, lane = 2 channels
  const float* hb = h + (size_t)b * N_ * COUT;
  float2 acc = make_float2(-__builtin_inff(), -__builtin_inff());
#pragma unroll
  for (int i = 0; i < K_; i++) {
    const int n = winLds[wv][i];                // LDS broadcast read
    float2 v = *(const float2*)(hb + (size_t)n * COUT + lane * 2);
    acc.x = fmaxf(acc.x, v.x);
    acc.y = fmaxf(acc.y, v.y);
  }
  *(float2*)(y + (size_t)q * COUT + lane * 2) = acc;
}

// ---------------------------------------------------------------------------
extern "C" void kernel_launch(void* const* d_in, const int* in_sizes, int n_in,
                              void* d_out, int out_size, void* d_ws, size_t ws_size,
                              hipStream_t stream) {
  const float* x     = (const float*)d_in[0];
  const float* p     = (const float*)d_in[1];
  const float* W     = (const float*)d_in[2];
  const float* gamma = (const float*)d_in[3];
  const float* beta  = (const float*)d_in[4];
  const float* rmean = (const float*)d_in[5];
  const float* rvar  = (const float*)d_in[6];

  float* y     = (float*)d_out;                       // (B, M, COUT)
  float* p_out = y + (size_t)B_ * M_ * COUT;          // (B, M, 3)
  float* h     = (float*)d_ws;                        // (B, N, COUT) scratch

  mlp_kernel<<<(B_ * N_ * COUT) / 256, 256, 0, stream>>>(
      x, W, gamma, beta, rmean, rvar, h);
  fps_kernel<<<B_, FTH, 0, stream>>>(p, p_out);
  knn_kernel<<<B_ * (M_ / QPB), 1024, 0, stream>>>(p, p_out, h, y);
}

// Round 11
// 2284.821 us; speedup vs baseline: 1.2957x; 1.1107x over previous
//
#include <hip/hip_runtime.h>

#define B_   8
#define N_   8192
#define CIN  64
#define COUT 128
#define M_   2048
#define K_   16

// ---------------------------------------------------------------------------
// DPP wave-64 reduce helpers (VALU-only, no LDS latency).
// ---------------------------------------------------------------------------
template <int CTRL>
__device__ __forceinline__ unsigned long long dpp64(unsigned long long x) {
  int lo = (int)(unsigned)(x & 0xFFFFFFFFull);
  int hi = (int)(unsigned)(x >> 32);
  int dlo = __builtin_amdgcn_update_dpp(lo, lo, CTRL, 0xF, 0xF, false);
  int dhi = __builtin_amdgcn_update_dpp(hi, hi, CTRL, 0xF, 0xF, false);
  return ((unsigned long long)(unsigned)dhi << 32) | (unsigned)dlo;
}

__device__ __forceinline__ unsigned long long readlane63_u64(unsigned long long k) {
  unsigned lo = (unsigned)__builtin_amdgcn_readlane((int)(unsigned)(k & 0xFFFFFFFFull), 63);
  unsigned hi = (unsigned)__builtin_amdgcn_readlane((int)(unsigned)(k >> 32), 63);
  return ((unsigned long long)hi << 32) | lo;
}

__device__ __forceinline__ unsigned long long wave_max_u64(unsigned long long k) {
  unsigned long long t;
  t = dpp64<0x111>(k); k = t > k ? t : k;   // row_shr:1
  t = dpp64<0x112>(k); k = t > k ? t : k;   // row_shr:2
  t = dpp64<0x114>(k); k = t > k ? t : k;   // row_shr:4
  t = dpp64<0x118>(k); k = t > k ? t : k;   // row_shr:8
  t = dpp64<0x142>(k); k = t > k ? t : k;   // row_bcast:15
  t = dpp64<0x143>(k); k = t > k ? t : k;   // row_bcast:31
  return readlane63_u64(k);
}

__device__ __forceinline__ unsigned long long wave_min_u64(unsigned long long k) {
  unsigned long long t;
  t = dpp64<0x111>(k); k = t < k ? t : k;
  t = dpp64<0x112>(k); k = t < k ? t : k;
  t = dpp64<0x114>(k); k = t < k ? t : k;
  t = dpp64<0x118>(k); k = t < k ? t : k;
  t = dpp64<0x142>(k); k = t < k ? t : k;
  t = dpp64<0x143>(k); k = t < k ? t : k;
  return readlane63_u64(k);
}

// ---------------------------------------------------------------------------
// 1) Pointwise MLP — L1-transaction fix. Old version: lane i read W[o=i][c]
//    (256 B lane stride -> 64 cache lines per load instr -> ~430 us).
//    New: 256-thread block computes 16 rows x 128 o. W staged TRANSPOSED in
//    LDS (wt[c][o], pad 132 -> conflict-free reads: lanes scan consecutive
//    o). x rows staged as float4 (coalesced). Each thread: 8 rows for its o,
//    accumulated over c in ascending float4 chunks — SAME summation order
//    as the previous passing kernel.
// ---------------------------------------------------------------------------
#define MROWS 16   // rows per block

__global__ __launch_bounds__(256) void mlp_kernel(
    const float* __restrict__ x, const float* __restrict__ W,
    const float* __restrict__ gamma, const float* __restrict__ beta,
    const float* __restrict__ rmean, const float* __restrict__ rvar,
    float* __restrict__ h) {
  __shared__ float wt[CIN * 132];               // W^T, padded: wt[c*132+o]
  __shared__ float xs[MROWS * CIN];             // xs[r*64+c]

  const int t  = threadIdx.x;
  const int o  = t & 127;
  const int rg = t >> 7;                        // 0 or 1 -> rows rg*8..rg*8+7
  const int rowBase = blockIdx.x * MROWS;

  // stage W transposed: idx -> (o = idx>>6, c = idx&63); coalesced reads
  for (int idx = t; idx < COUT * CIN; idx += 256) {
    const int oo = idx >> 6, cc = idx & 63;
    wt[cc * 132 + oo] = W[idx];
  }
  // stage 16 x rows as float4 (256 f4 = one per thread)
  ((float4*)xs)[t] = ((const float4*)(x + (size_t)rowBase * CIN))[t];
  __syncthreads();

  float acc[8] = {0.f, 0.f, 0.f, 0.f, 0.f, 0.f, 0.f, 0.f};
#pragma unroll
  for (int c4 = 0; c4 < CIN / 4; c4++) {
    const float w0 = wt[(4 * c4 + 0) * 132 + o];
    const float w1 = wt[(4 * c4 + 1) * 132 + o];
    const float w2 = wt[(4 * c4 + 2) * 132 + o];
    const float w3 = wt[(4 * c4 + 3) * 132 + o];
#pragma unroll
    for (int i = 0; i < 8; i++) {
      const float4 xv = *(const float4*)&xs[(rg * 8 + i) * CIN + c4 * 4];
      acc[i] += xv.x * w0 + xv.y * w1 + xv.z * w2 + xv.w * w3;
    }
  }

  const float mu = rmean[o];
  const float sc = rsqrtf(rvar[o] + 1e-5f) * gamma[o];
  const float bt = beta[o];
#pragma unroll
  for (int i = 0; i < 8; i++) {
    const float v = (acc[i] - mu) * sc + bt;
    h[(size_t)(rowBase + rg * 8 + i) * COUT + o] = fmaxf(v, 0.f);
  }
}

// ---------------------------------------------------------------------------
// 2) FPS — VERBATIM from R9/R10 (passing, ~1967 us). Numerics: f32 strict
//    numpy order ((dx^2+dy^2)+dz^2) no-FMA, fminf, u64 (d<<32)|(N-1-n).
// ---------------------------------------------------------------------------
#define FTH 512
#define FPT 16   // points per thread = N_/FTH

__global__ __launch_bounds__(512) void fps_kernel(
    const float* __restrict__ p, float* __restrict__ p_out) {
#pragma clang fp contract(off)
  __shared__ float4 pc4[N_];                            // 128 KB
  __shared__ __align__(16) unsigned long long wred[2][8];
  __shared__ int idxHist[M_];                           // 8 KB

  const int b   = blockIdx.x;
  const int tid = threadIdx.x;
  const int wv  = tid >> 6;
  const int ln  = tid & 63;

  const float* pb = p + (size_t)b * N_ * 3;
  for (int n = tid; n < N_; n += FTH)
    pc4[n] = make_float4(pb[3 * n + 0], pb[3 * n + 1], pb[3 * n + 2], 0.f);
  if (tid == 0) idxHist[0] = 0;
  __syncthreads();

  float4 c0 = pc4[0];
  float cx = c0.x, cy = c0.y, cz = c0.z;

  float X[FPT], Y[FPT], Z[FPT], D[FPT];
#pragma unroll
  for (int k = 0; k < FPT; k++) {
    float4 v = pc4[tid + k * FTH];
    X[k] = v.x; Y[k] = v.y; Z[k] = v.z;
    D[k] = __builtin_inff();
  }

  int buf = 0;
  for (int it = 1; it < M_; ++it) {
    float bd = -1.0f; int bk = 0;
#pragma unroll
    for (int k = 0; k < FPT; k++) {
      float dx = X[k] - cx, dy = Y[k] - cy, dz = Z[k] - cz;
      float d  = (dx * dx + dy * dy) + dz * dz; // numpy sum order, no fma
      float dm = fminf(D[k], d);
      D[k] = dm;
      if (dm > bd) { bd = dm; bk = k; }         // strict > keeps min k (min n)
    }
    const int n = tid + (bk << 9);              // bk*512
    unsigned long long key =
        ((unsigned long long)__float_as_uint(bd) << 32) |
        (unsigned)(N_ - 1 - n);                 // max key => max d, min n
    key = wave_max_u64(key);                    // DPP reduce (uniform result)
    if (ln == 0) wred[buf][wv] = key;
    __syncthreads();                            // the ONLY barrier per iter
    const ulonglong2* wp = (const ulonglong2*)(&wred[buf][0]);
    ulonglong2 w0 = wp[0], w1 = wp[1], w2 = wp[2], w3 = wp[3];
    unsigned long long m0 = w0.x > w0.y ? w0.x : w0.y;
    unsigned long long m1 = w1.x > w1.y ? w1.x : w1.y;
    unsigned long long m2 = w2.x > w2.y ? w2.x : w2.y;
    unsigned long long m3 = w3.x > w3.y ? w3.x : w3.y;
    m0 = m0 > m1 ? m0 : m1;
    m2 = m2 > m3 ? m2 : m3;
    m0 = m0 > m2 ? m0 : m2;
    const int nw = N_ - 1 - (int)(unsigned)(m0 & 0xFFFFFFFFu);
    float4 cc = pc4[nw];                        // 1 broadcast b128
    cx = cc.x; cy = cc.y; cz = cc.z;
    if (tid == 0) idxHist[it] = nw;
    buf ^= 1;
  }
  __syncthreads();

  float* po = p_out + (size_t)b * M_ * 3;
  for (int mi = tid; mi < M_; mi += FTH) {
    float4 v = pc4[idxHist[mi]];
    po[mi * 3 + 0] = v.x;
    po[mi * 3 + 1] = v.y;
    po[mi * 3 + 2] = v.z;
  }
}

// ---------------------------------------------------------------------------
// 3) KNN — VERBATIM from R10 (passing). 16 queries/block, p[b]+sn staged in
//    LDS once per block; per-lane sorted top-4 cache, 16 DPP-min rounds,
//    exact rescan; fused gather/max-pool. d2 bits identical to R5-R10.
// ---------------------------------------------------------------------------
#define UMAXK 0xFFFFFFFFFFFFFFFFull
#define QPB  16   // queries (waves) per block

__global__ __launch_bounds__(1024) void knn_kernel(
    const float* __restrict__ p, const float* __restrict__ p_out,
    const float* __restrict__ h, float* __restrict__ y) {
#pragma clang fp contract(off)
  __shared__ float4 pc4[N_];            // 128 KB: x,y,z,sn
  __shared__ int winLds[QPB][K_];

  const int t    = threadIdx.x;
  const int wv   = t >> 6;
  const int lane = t & 63;
  const int b    = blockIdx.x & 7;      // batch: keeps h[b] on one XCD (heur.)
  const int grp  = blockIdx.x >> 3;     // 0..127
  const int q    = b * M_ + grp * QPB + wv;

  const float* pb = p + (size_t)b * N_ * 3;
  for (int n = t; n < N_; n += 1024) {
    float xx = pb[3 * n + 0], yy = pb[3 * n + 1], zz = pb[3 * n + 2];
    float sn = (xx * xx + yy * yy) + zz * zz;   // numpy sum, no fma
    pc4[n] = make_float4(xx, yy, zz, sn);
  }
  __syncthreads();

  const float qx = p_out[q * 3 + 0];
  const float qy = p_out[q * 3 + 1];
  const float qz = p_out[q * 3 + 2];
  const float sq = (qx * qx + qy * qy) + qz * qz;   // numpy sum, no fma

  unsigned long long c0 = UMAXK, c1 = UMAXK, c2 = UMAXK, c3 = UMAXK;
#pragma unroll 4
  for (int j = 0; j < 128; j++) {
    const int n = lane + (j << 6);
    float4 v = pc4[n];
    float dot = __builtin_fmaf(qz, v.z,
                __builtin_fmaf(qy, v.y, qx * v.x)); // BLAS fma chain, k asc
    float d2 = (sq + v.w) - 2.0f * dot;
    unsigned u = __float_as_uint(d2);
    u ^= (unsigned)((int)u >> 31) | 0x80000000u;    // monotone f32->u32
    unsigned long long key = ((unsigned long long)u << 32) | (unsigned)n;
    if (key < c3) {
      unsigned long long x = key, mn;
      mn = x < c0 ? x : c0; x = x < c0 ? c0 : x; c0 = mn;
      mn = x < c1 ? x : c1; x = x < c1 ? c1 : x; c1 = mn;
      mn = x < c2 ? x : c2; x = x < c2 ? c2 : x; c2 = mn;
      c3 = x < c3 ? x : c3;
    }
  }

  int count = 4;
  unsigned long long em0 = 0ull, em1 = 0ull;    // extraction mask (128 bits)
  unsigned long long mykey = UMAXK;             // lane r keeps round-r winner

  for (int k = 0; k < K_; k++) {
    unsigned long long cnd = (count > 0) ? c0 : UMAXK;
    unsigned long long win = wave_min_u64(cnd); // uniform; unique n => exact
    if (lane == k) mykey = win;
    const int nstar = (int)(unsigned)(win & 0xFFFFFFFFu);
    if ((nstar & 63) == lane) {                 // I own the winner (== my c0)
      const int j = nstar >> 6;
      if (j < 64) em0 |= 1ull << j; else em1 |= 1ull << (j - 64);
      c0 = c1; c1 = c2; c2 = c3; c3 = UMAXK; count--;
      if (count == 0 && k < K_ - 1) {           // rare exact rescan from LDS
        c0 = c1 = c2 = c3 = UMAXK;
        for (int j2 = 0; j2 < 128; j2++) {
          bool ex = (j2 < 64) ? ((em0 >> j2) & 1ull) : ((em1 >> (j2 - 64)) & 1ull);
          if (!ex) {
            const int n2 = lane + (j2 << 6);
            float4 v = pc4[n2];
            float dot = __builtin_fmaf(qz, v.z,
                        __builtin_fmaf(qy, v.y, qx * v.x));
            float d2 = (sq + v.w) - 2.0f * dot;
            unsigned u = __float_as_uint(d2);
            u ^= (unsigned)((int)u >> 31) | 0x80000000u;
            unsigned long long kk = ((unsigned long long)u << 32) | (unsigned)n2;
            if (kk < c3) {
              unsigned long long x = kk, mn;
              mn = x < c0 ? x : c0; x = x < c0 ? c0 : x; c0 = mn;
              mn = x < c1 ? x : c1; x = x < c1 ? c1 : x; c1 = mn;
              mn = x < c2 ? x : c2; x = x < c2 ? c2 : x; c2 = mn;
              c3 = x < c3 ? x : c3;
            }
          }
        }
        count = 4;
      }
    }
  }

  if (lane < K_) winLds[wv][lane] = (int)(unsigned)(mykey & 0xFFFFFFFFu);
  __syncthreads();

  const float* hb = h + (size_t)b * N_ * COUT;
  float2 acc = make_float2(-__builtin_inff(), -__builtin_inff());
#pragma unroll
  for (int i = 0; i < K_; i++) {
    const int n = winLds[wv][i];                // LDS broadcast read
    float2 v = *(const float2*)(hb + (size_t)n * COUT + lane * 2);
    acc.x = fmaxf(acc.x, v.x);
    acc.y = fmaxf(acc.y, v.y);
  }
  *(float2*)(y + (size_t)q * COUT + lane * 2) = acc;
}

// ---------------------------------------------------------------------------
extern "C" void kernel_launch(void* const* d_in, const int* in_sizes, int n_in,
                              void* d_out, int out_size, void* d_ws, size_t ws_size,
                              hipStream_t stream) {
  const float* x     = (const float*)d_in[0];
  const float* p     = (const float*)d_in[1];
  const float* W     = (const float*)d_in[2];
  const float* gamma = (const float*)d_in[3];
  const float* beta  = (const float*)d_in[4];
  const float* rmean = (const float*)d_in[5];
  const float* rvar  = (const float*)d_in[6];

  float* y     = (float*)d_out;                       // (B, M, COUT)
  float* p_out = y + (size_t)B_ * M_ * COUT;          // (B, M, 3)
  float* h     = (float*)d_ws;                        // (B, N, COUT) scratch

  mlp_kernel<<<(B_ * N_) / MROWS, 256, 0, stream>>>(
      x, W, gamma, beta, rmean, rvar, h);
  fps_kernel<<<B_, FTH, 0, stream>>>(p, p_out);
  knn_kernel<<<B_ * (M_ / QPB), 1024, 0, stream>>>(p, p_out, h, y);
}

// Round 12
// 2117.224 us; speedup vs baseline: 1.3982x; 1.0792x over previous
//
#include <hip/hip_runtime.h>

#define B_   8
#define N_   8192
#define CIN  64
#define COUT 128
#define M_   2048
#define K_   16

typedef float v2f __attribute__((ext_vector_type(2)));

// ---------------------------------------------------------------------------
// DPP wave-64 reduce helpers (VALU-only, no LDS latency).
// ---------------------------------------------------------------------------
template <int CTRL>
__device__ __forceinline__ unsigned long long dpp64(unsigned long long x) {
  int lo = (int)(unsigned)(x & 0xFFFFFFFFull);
  int hi = (int)(unsigned)(x >> 32);
  int dlo = __builtin_amdgcn_update_dpp(lo, lo, CTRL, 0xF, 0xF, false);
  int dhi = __builtin_amdgcn_update_dpp(hi, hi, CTRL, 0xF, 0xF, false);
  return ((unsigned long long)(unsigned)dhi << 32) | (unsigned)dlo;
}

__device__ __forceinline__ unsigned long long readlane_u64(unsigned long long k, int l) {
  unsigned lo = (unsigned)__builtin_amdgcn_readlane((int)(unsigned)(k & 0xFFFFFFFFull), l);
  unsigned hi = (unsigned)__builtin_amdgcn_readlane((int)(unsigned)(k >> 32), l);
  return ((unsigned long long)hi << 32) | lo;
}

__device__ __forceinline__ unsigned long long wave_max_u64(unsigned long long k) {
  unsigned long long t;
  t = dpp64<0x111>(k); k = t > k ? t : k;   // row_shr:1
  t = dpp64<0x112>(k); k = t > k ? t : k;   // row_shr:2
  t = dpp64<0x114>(k); k = t > k ? t : k;   // row_shr:4
  t = dpp64<0x118>(k); k = t > k ? t : k;   // row_shr:8
  t = dpp64<0x142>(k); k = t > k ? t : k;   // row_bcast:15
  t = dpp64<0x143>(k); k = t > k ? t : k;   // row_bcast:31
  return readlane_u64(k, 63);
}

__device__ __forceinline__ unsigned long long wave_min_u64(unsigned long long k) {
  unsigned long long t;
  t = dpp64<0x111>(k); k = t < k ? t : k;
  t = dpp64<0x112>(k); k = t < k ? t : k;
  t = dpp64<0x114>(k); k = t < k ? t : k;
  t = dpp64<0x118>(k); k = t < k ? t : k;
  t = dpp64<0x142>(k); k = t < k ? t : k;
  t = dpp64<0x143>(k); k = t < k ? t : k;
  return readlane_u64(k, 63);
}

// ---------------------------------------------------------------------------
// 1+2) Merged FPS + MLP kernel. Blocks 0..7: FPS (one per batch). Blocks
//      8..2055: MLP tiles (32 rows each) — they fill the other 248 CUs while
//      the 8 FPS blocks grind, hiding the MLP entirely.
//      Shared-mem union sized for FPS (136.5 KB -> 1 block/CU either kind).
//
//      FPS numerics identical to R5-R11 passing chain: f32 strict numpy order
//      ((dx^2+dy^2)+dz^2) NO-FMA (contract off; pk ops are element-wise IEEE
//      identical), fminf, u64 (d<<32)|(N-1-n) argmax = (max d, min n).
//      Points processed in PAIRS as <2 x float> so the compiler emits
//      v_pk_add/mul_f32 (2 f32/instr); argmax stays scalar .x then .y which
//      preserves the ascending-k (= ascending-n) first-index semantics.
//
//      MLP numerics identical to R11: ascending-c4 float4 chunks, inner
//      4-term order xv.x*w0 + xv.y*w1 + xv.z*w2 + xv.w*w3.
// ---------------------------------------------------------------------------
#define FTH 512
#define FPT 16    // points per thread = N_/FTH
#define MROWS2 32 // rows per mlp block (512 threads)

__global__ __launch_bounds__(512) void fps_mlp_kernel(
    const float* __restrict__ p, float* __restrict__ p_out,
    const float* __restrict__ x, const float* __restrict__ W,
    const float* __restrict__ gamma, const float* __restrict__ beta,
    const float* __restrict__ rmean, const float* __restrict__ rvar,
    float* __restrict__ h) {
#pragma clang fp contract(off)
  __shared__ __align__(16) unsigned char smem[139776];

  const int tid = threadIdx.x;

  if (blockIdx.x >= 8) {
    // ---------------- MLP tile ----------------
    float* wt = (float*)smem;                   // W^T padded: wt[c*132+o]
    float* xs = (float*)(smem + 33792);         // xs[r*64+c], 32 rows

    const int o  = tid & 127;
    const int rg = tid >> 7;                    // 0..3 -> rows rg*8..rg*8+7
    const int rowBase = (blockIdx.x - 8) * MROWS2;

    for (int idx = tid; idx < COUT * CIN; idx += 512) {
      const int oo = idx >> 6, cc = idx & 63;
      wt[cc * 132 + oo] = W[idx];
    }
    ((float4*)xs)[tid] = ((const float4*)(x + (size_t)rowBase * CIN))[tid];
    __syncthreads();

    float acc[8] = {0.f, 0.f, 0.f, 0.f, 0.f, 0.f, 0.f, 0.f};
#pragma unroll
    for (int c4 = 0; c4 < CIN / 4; c4++) {
      const float w0 = wt[(4 * c4 + 0) * 132 + o];
      const float w1 = wt[(4 * c4 + 1) * 132 + o];
      const float w2 = wt[(4 * c4 + 2) * 132 + o];
      const float w3 = wt[(4 * c4 + 3) * 132 + o];
#pragma unroll
      for (int i = 0; i < 8; i++) {
        const float4 xv = *(const float4*)&xs[(rg * 8 + i) * CIN + c4 * 4];
        acc[i] += xv.x * w0 + xv.y * w1 + xv.z * w2 + xv.w * w3;
      }
    }
    const float mu = rmean[o];
    const float sc = rsqrtf(rvar[o] + 1e-5f) * gamma[o];
    const float bt = beta[o];
#pragma unroll
    for (int i = 0; i < 8; i++) {
      const float v = (acc[i] - mu) * sc + bt;
      h[(size_t)(rowBase + rg * 8 + i) * COUT + o] = fmaxf(v, 0.f);
    }
    return;
  }

  // ---------------- FPS ----------------
  float4* pc4 = (float4*)smem;                               // 128 KB
  unsigned long long (*wred)[8] =
      (unsigned long long (*)[8])(smem + 131072);            // 2*8*8 B
  int* idxHist = (int*)(smem + 131072 + 128);                // 8 KB

  const int b  = blockIdx.x;
  const int wv = tid >> 6;
  const int ln = tid & 63;

  const float* pb = p + (size_t)b * N_ * 3;
  for (int n = tid; n < N_; n += FTH)
    pc4[n] = make_float4(pb[3 * n + 0], pb[3 * n + 1], pb[3 * n + 2], 0.f);
  if (tid == 0) idxHist[0] = 0;
  __syncthreads();

  float4 c0 = pc4[0];
  float cx = c0.x, cy = c0.y, cz = c0.z;

  // pairs: element e of pair j is point n = tid + (2j+e)*512
  v2f X2[8], Y2[8], Z2[8], D2[8];
#pragma unroll
  for (int j = 0; j < 8; j++) {
    float4 a = pc4[tid + (2 * j) * FTH];
    float4 c = pc4[tid + (2 * j + 1) * FTH];
    X2[j] = (v2f){a.x, c.x};
    Y2[j] = (v2f){a.y, c.y};
    Z2[j] = (v2f){a.z, c.z};
    D2[j] = (v2f){__builtin_inff(), __builtin_inff()};
  }

  int buf = 0;
  for (int it = 1; it < M_; ++it) {
    const v2f cxv = {cx, cx}, cyv = {cy, cy}, czv = {cz, cz};
    float bd = -1.0f; int bk = 0;
#pragma unroll
    for (int j = 0; j < 8; j++) {
      v2f dx = X2[j] - cxv;
      v2f dy = Y2[j] - cyv;
      v2f dz = Z2[j] - czv;
      v2f m1 = dx * dx;
      v2f m2 = dy * dy;
      v2f s  = m1 + m2;
      v2f m3 = dz * dz;
      v2f d  = s + m3;                           // numpy order, no fma
      v2f dm = __builtin_elementwise_min(D2[j], d);
      D2[j] = dm;
      if (dm.x > bd) { bd = dm.x; bk = 2 * j; }      // k asc -> first max
      if (dm.y > bd) { bd = dm.y; bk = 2 * j + 1; }
    }
    const int n = tid + (bk << 9);              // bk*512
    unsigned long long key =
        ((unsigned long long)__float_as_uint(bd) << 32) |
        (unsigned)(N_ - 1 - n);                 // max key => max d, min n
    key = wave_max_u64(key);                    // DPP reduce (uniform)
    if (ln == 0) wred[buf][wv] = key;
    __syncthreads();                            // the ONLY barrier per iter
    // lane-parallel decode: lanes 0..7 load the 8 wave keys, 3-stage DPP max
    unsigned long long kk = wred[buf][ln & 7];
    unsigned long long t;
    t = dpp64<0x111>(kk); kk = t > kk ? t : kk;
    t = dpp64<0x112>(kk); kk = t > kk ? t : kk;
    t = dpp64<0x114>(kk); kk = t > kk ? t : kk;
    const unsigned long long m = readlane_u64(kk, 7);
    const int nw = N_ - 1 - (int)(unsigned)(m & 0xFFFFFFFFu);
    float4 cc = pc4[nw];                        // 1 broadcast b128
    cx = cc.x; cy = cc.y; cz = cc.z;
    if (tid == 0) idxHist[it] = nw;
    buf ^= 1;
  }
  __syncthreads();

  float* po = p_out + (size_t)b * M_ * 3;
  for (int mi = tid; mi < M_; mi += FTH) {
    float4 v = pc4[idxHist[mi]];
    po[mi * 3 + 0] = v.x;
    po[mi * 3 + 1] = v.y;
    po[mi * 3 + 2] = v.z;
  }
}

// ---------------------------------------------------------------------------
// 3) KNN — VERBATIM from R10/R11 (passing). 16 queries/block, p[b]+sn staged
//    in LDS once per block; per-lane sorted top-4 cache, 16 DPP-min rounds,
//    exact rescan; fused gather/max-pool. d2 bits identical to R5-R11.
// ---------------------------------------------------------------------------
#define UMAXK 0xFFFFFFFFFFFFFFFFull
#define QPB  16   // queries (waves) per block

__global__ __launch_bounds__(1024) void knn_kernel(
    const float* __restrict__ p, const float* __restrict__ p_out,
    const float* __restrict__ h, float* __restrict__ y) {
#pragma clang fp contract(off)
  __shared__ float4 pc4[N_];            // 128 KB: x,y,z,sn
  __shared__ int winLds[QPB][K_];

  const int t    = threadIdx.x;
  const int wv   = t >> 6;
  const int lane = t & 63;
  const int b    = blockIdx.x & 7;      // batch: keeps h[b] on one XCD (heur.)
  const int grp  = blockIdx.x >> 3;     // 0..127
  const int q    = b * M_ + grp * QPB + wv;

  const float* pb = p + (size_t)b * N_ * 3;
  for (int n = t; n < N_; n += 1024) {
    float xx = pb[3 * n + 0], yy = pb[3 * n + 1], zz = pb[3 * n + 2];
    float sn = (xx * xx + yy * yy) + zz * zz;   // numpy sum, no fma
    pc4[n] = make_float4(xx, yy, zz, sn);
  }
  __syncthreads();

  const float qx = p_out[q * 3 + 0];
  const float qy = p_out[q * 3 + 1];
  const float qz = p_out[q * 3 + 2];
  const float sq = (qx * qx + qy * qy) + qz * qz;   // numpy sum, no fma

  unsigned long long c0 = UMAXK, c1 = UMAXK, c2 = UMAXK, c3 = UMAXK;
#pragma unroll 4
  for (int j = 0; j < 128; j++) {
    const int n = lane + (j << 6);
    float4 v = pc4[n];
    float dot = __builtin_fmaf(qz, v.z,
                __builtin_fmaf(qy, v.y, qx * v.x)); // BLAS fma chain, k asc
    float d2 = (sq + v.w) - 2.0f * dot;
    unsigned u = __float_as_uint(d2);
    u ^= (unsigned)((int)u >> 31) | 0x80000000u;    // monotone f32->u32
    unsigned long long key = ((unsigned long long)u << 32) | (unsigned)n;
    if (key < c3) {
      unsigned long long x2 = key, mn;
      mn = x2 < c0 ? x2 : c0; x2 = x2 < c0 ? c0 : x2; c0 = mn;
      mn = x2 < c1 ? x2 : c1; x2 = x2 < c1 ? c1 : x2; c1 = mn;
      mn = x2 < c2 ? x2 : c2; x2 = x2 < c2 ? c2 : x2; c2 = mn;
      c3 = x2 < c3 ? x2 : c3;
    }
  }

  int count = 4;
  unsigned long long em0 = 0ull, em1 = 0ull;    // extraction mask (128 bits)
  unsigned long long mykey = UMAXK;             // lane r keeps round-r winner

  for (int k = 0; k < K_; k++) {
    unsigned long long cnd = (count > 0) ? c0 : UMAXK;
    unsigned long long win = wave_min_u64(cnd); // uniform; unique n => exact
    if (lane == k) mykey = win;
    const int nstar = (int)(unsigned)(win & 0xFFFFFFFFu);
    if ((nstar & 63) == lane) {                 // I own the winner (== my c0)
      const int j = nstar >> 6;
      if (j < 64) em0 |= 1ull << j; else em1 |= 1ull << (j - 64);
      c0 = c1; c1 = c2; c2 = c3; c3 = UMAXK; count--;
      if (count == 0 && k < K_ - 1) {           // rare exact rescan from LDS
        c0 = c1 = c2 = c3 = UMAXK;
        for (int j2 = 0; j2 < 128; j2++) {
          bool ex = (j2 < 64) ? ((em0 >> j2) & 1ull) : ((em1 >> (j2 - 64)) & 1ull);
          if (!ex) {
            const int n2 = lane + (j2 << 6);
            float4 v = pc4[n2];
            float dot = __builtin_fmaf(qz, v.z,
                        __builtin_fmaf(qy, v.y, qx * v.x));
            float d2 = (sq + v.w) - 2.0f * dot;
            unsigned u = __float_as_uint(d2);
            u ^= (unsigned)((int)u >> 31) | 0x80000000u;
            unsigned long long kk2 = ((unsigned long long)u << 32) | (unsigned)n2;
            if (kk2 < c3) {
              unsigned long long x2 = kk2, mn;
              mn = x2 < c0 ? x2 : c0; x2 = x2 < c0 ? c0 : x2; c0 = mn;
              mn = x2 < c1 ? x2 : c1; x2 = x2 < c1 ? c1 : x2; c1 = mn;
              mn = x2 < c2 ? x2 : c2; x2 = x2 < c2 ? c2 : x2; c2 = mn;
              c3 = x2 < c3 ? x2 : c3;
            }
          }
        }
        count = 4;
      }
    }
  }

  if (lane < K_) winLds[wv][lane] = (int)(unsigned)(mykey & 0xFFFFFFFFu);
  __syncthreads();

  const float* hb = h + (size_t)b * N_ * COUT;
  float2 acc = make_float2(-__builtin_inff(), -__builtin_inff());
#pragma unroll
  for (int i = 0; i < K_; i++) {
    const int n = winLds[wv][i];                // LDS broadcast read
    float2 v = *(const float2*)(hb + (size_t)n * COUT + lane * 2);
    acc.x = fmaxf(acc.x, v.x);
    acc.y = fmaxf(acc.y, v.y);
  }
  *(float2*)(y + (size_t)q * COUT + lane * 2) = acc;
}

// ---------------------------------------------------------------------------
extern "C" void kernel_launch(void* const* d_in, const int* in_sizes, int n_in,
                              void* d_out, int out_size, void* d_ws, size_t ws_size,
                              hipStream_t stream) {
  const float* x     = (const float*)d_in[0];
  const float* p     = (const float*)d_in[1];
  const float* W     = (const float*)d_in[2];
  const float* gamma = (const float*)d_in[3];
  const float* beta  = (const float*)d_in[4];
  const float* rmean = (const float*)d_in[5];
  const float* rvar  = (const float*)d_in[6];

  float* y     = (float*)d_out;                       // (B, M, COUT)
  float* p_out = y + (size_t)B_ * M_ * COUT;          // (B, M, 3)
  float* h     = (float*)d_ws;                        // (B, N, COUT) scratch

  fps_mlp_kernel<<<8 + (B_ * N_) / MROWS2, 512, 0, stream>>>(
      p, p_out, x, W, gamma, beta, rmean, rvar, h);
  knn_kernel<<<B_ * (M_ / QPB), 1024, 0, stream>>>(p, p_out, h, y);
}